// Round 6
// baseline (124.479 us; speedup 1.0000x reference)
//
#include <hip/hip_runtime.h>
#include <hip/hip_cooperative_groups.h>
#include <math.h>

namespace cg = cooperative_groups;

#define BB 128   // batch
#define VV 4     // views
#define NN 512   // BB*VV rows
#define DD 128   // feature dim
#define NT 256   // threads per block

// ---------------------------------------------------------------------------
// Single cooperative kernel, one block per anchor (512 blocks = 2/CU).
// Phase 1 (R4-proven): fused sweep over all 512 rows computes ss_j and
//   dot_j(anchor) with 8 lanes/row, 4 float4 loads/lane, butterfly reduce.
//   Anchor fragments in NAMED scalars af0..af3 — R5 used indexed arrays and
//   the compiler demoted them to scratch (VGPR_Count 32, 44.9 us kernel).
// Phase 2: d_j = sqrt(max(sn_a + sn_j - 2*dot*inv_a*inv_j, 0)) (== reference
//   normalize-then-dot to ~1e-7; absmax 0.0 in rounds 2-5), ballot
//   compaction into pos/neg lists, relu pair loop.
// Phase 3: block reduce -> psum/pcnt partials; grid.sync(); block 0 reduces
//   512 partials and writes out = C>0 ? S/C : 0.
// Deterministic; no global atomics; ws write-before-read (no init needed).
// ---------------------------------------------------------------------------
__global__ __launch_bounds__(NT)
void fused_all(const float* __restrict__ feat,
               const int* __restrict__ labels,
               float* __restrict__ psum,
               float* __restrict__ pcnt,
               float* __restrict__ out) {
    __shared__ float s_ss[NN];
    __shared__ float s_dot[NN];
    __shared__ float s_pos[NN];
    __shared__ float s_neg[NN];
    __shared__ int   s_lab[BB];
    __shared__ int   s_np, s_nn;
    __shared__ float s_wsum[NT / 64];
    __shared__ unsigned int s_wcnt[NT / 64];

    const int a    = blockIdx.x;
    const int tid  = threadIdx.x;
    const int wave = tid >> 6;      // 0..3
    const int lane = tid & 63;
    const int grp  = lane >> 3;     // 8 row-groups of 8 lanes
    const int l8   = lane & 7;

    if (tid < BB) s_lab[tid] = labels[tid];
    if (tid == 0) { s_np = 0; s_nn = 0; }

    // anchor row fragments: this lane's 4 float4s — NAMED scalars (see above)
    const int ab = a & (BB - 1), av = a >> 7;
    const float4* arow = (const float4*)(feat + (size_t)ab * (VV * DD) + av * DD);
    float4 af0 = arow[l8];
    float4 af1 = arow[l8 + 8];
    float4 af2 = arow[l8 + 16];
    float4 af3 = arow[l8 + 24];

    // Phase 1: fused ss + dot sweep; wave w covers rows [w*128, w*128+128)
    #pragma unroll 4
    for (int it = 0; it < 16; ++it) {
        const int j  = (wave << 7) + (it << 3) + grp;
        const int jb = j & (BB - 1), jv = j >> 7;
        const float4* jrow = (const float4*)(feat + (size_t)jb * (VV * DD) + jv * DD);
        float4 x0 = jrow[l8];
        float4 x1 = jrow[l8 + 8];
        float4 x2 = jrow[l8 + 16];
        float4 x3 = jrow[l8 + 24];

        float ss = 0.f, dt = 0.f;
        ss = fmaf(x0.x, x0.x, fmaf(x0.y, x0.y, fmaf(x0.z, x0.z, fmaf(x0.w, x0.w, ss))));
        ss = fmaf(x1.x, x1.x, fmaf(x1.y, x1.y, fmaf(x1.z, x1.z, fmaf(x1.w, x1.w, ss))));
        ss = fmaf(x2.x, x2.x, fmaf(x2.y, x2.y, fmaf(x2.z, x2.z, fmaf(x2.w, x2.w, ss))));
        ss = fmaf(x3.x, x3.x, fmaf(x3.y, x3.y, fmaf(x3.z, x3.z, fmaf(x3.w, x3.w, ss))));
        dt = fmaf(x0.x, af0.x, fmaf(x0.y, af0.y, fmaf(x0.z, af0.z, fmaf(x0.w, af0.w, dt))));
        dt = fmaf(x1.x, af1.x, fmaf(x1.y, af1.y, fmaf(x1.z, af1.z, fmaf(x1.w, af1.w, dt))));
        dt = fmaf(x2.x, af2.x, fmaf(x2.y, af2.y, fmaf(x2.z, af2.z, fmaf(x2.w, af2.w, dt))));
        dt = fmaf(x3.x, af3.x, fmaf(x3.y, af3.y, fmaf(x3.z, af3.z, fmaf(x3.w, af3.w, dt))));

        #pragma unroll
        for (int off = 4; off > 0; off >>= 1) {
            ss += __shfl_xor(ss, off);
            dt += __shfl_xor(dt, off);
        }
        if (l8 == 0) { s_ss[j] = ss; s_dot[j] = dt; }
    }
    __syncthreads();

    // Phase 2a: distances for j = tid, tid+256
    const float ssa  = s_ss[a];
    const float inva = 1.f / fmaxf(sqrtf(ssa), 1e-12f);
    const float sna  = ssa * inva * inva;
    float dreg[2];
    #pragma unroll
    for (int rnd = 0; rnd < 2; ++rnd) {
        const int j = tid + (rnd << 8);
        float ssj  = s_ss[j];
        float invj = 1.f / fmaxf(sqrtf(ssj), 1e-12f);
        float snj  = ssj * invj * invj;
        float dot  = s_dot[j] * inva * invj;
        float sq   = fmaxf(sna + snj - 2.f * dot, 0.f);
        dreg[rnd]  = (sq > 0.f) ? sqrtf(sq) : 0.f;   // safe_sqrt semantics
    }

    // Phase 2b: ballot compaction into pos/neg lists (8 LDS atomics/block)
    const int la = s_lab[a & (BB - 1)];
    #pragma unroll
    for (int rnd = 0; rnd < 2; ++rnd) {
        const int j = tid + (rnd << 8);
        bool same  = (s_lab[j & (BB - 1)] == la);
        bool ispos = same & (j != a);
        bool isneg = !same;
        unsigned long long mp = __ballot(ispos);
        unsigned long long mn = __ballot(isneg);
        int basep = 0, basen = 0;
        if (lane == 0) {
            basep = atomicAdd(&s_np, (int)__popcll(mp));
            basen = atomicAdd(&s_nn, (int)__popcll(mn));
        }
        basep = __shfl(basep, 0);
        basen = __shfl(basen, 0);
        unsigned long long below = (1ull << lane) - 1ull;
        if (ispos) s_pos[basep + (int)__popcll(mp & below)] = dreg[rnd];
        if (isneg) s_neg[basen + (int)__popcll(mn & below)] = dreg[rnd];
    }
    __syncthreads();

    // Phase 2c: pair loop — sum/count of relu(d_ap - d_an) > 0
    const int np = s_np, nneg = s_nn;
    float lsum = 0.f;
    unsigned int lcnt = 0;
    for (int p = 0; p < np; ++p) {
        float dp = s_pos[p];                 // LDS broadcast
        for (int n = tid; n < nneg; n += NT) {
            float diff = dp - s_neg[n];
            if (diff > 0.f) { lsum += diff; lcnt++; }
        }
    }

    // Phase 3: block reduce -> partials
    #pragma unroll
    for (int off = 32; off > 0; off >>= 1) {
        lsum += __shfl_down(lsum, off);
        lcnt += __shfl_down(lcnt, off);
    }
    if (lane == 0) { s_wsum[wave] = lsum; s_wcnt[wave] = lcnt; }
    __syncthreads();
    if (tid == 0) {
        psum[a] = s_wsum[0] + s_wsum[1] + s_wsum[2] + s_wsum[3];
        pcnt[a] = (float)(s_wcnt[0] + s_wcnt[1] + s_wcnt[2] + s_wcnt[3]);
    }

    // grid-wide barrier, then block 0 finalizes (512 partials, 256 threads)
    cg::this_grid().sync();

    if (blockIdx.x == 0) {
        float s = psum[tid] + psum[tid + NT];
        float c = pcnt[tid] + pcnt[tid + NT];
        #pragma unroll
        for (int off = 32; off > 0; off >>= 1) {
            s += __shfl_down(s, off);
            c += __shfl_down(c, off);
        }
        if (lane == 0) { s_wsum[wave] = s; s_wcnt[wave] = (unsigned int)c; }
        __syncthreads();
        if (tid == 0) {
            float S = s_wsum[0] + s_wsum[1] + s_wsum[2] + s_wsum[3];
            float C = (float)(s_wcnt[0] + s_wcnt[1] + s_wcnt[2] + s_wcnt[3]);
            out[0] = (C > 0.f) ? S / C : 0.f;
        }
    }
}

extern "C" void kernel_launch(void* const* d_in, const int* in_sizes, int n_in,
                              void* d_out, int out_size, void* d_ws, size_t ws_size,
                              hipStream_t stream) {
    const float* feat   = (const float*)d_in[0];   // [128, 4, 128] fp32
    const int*   labels = (const int*)d_in[1];     // [128] int32
    float* out = (float*)d_out;

    float* psum = (float*)d_ws;          // NN floats
    float* pcnt = psum + NN;             // NN floats

    void* args[] = { (void*)&feat, (void*)&labels, (void*)&psum,
                     (void*)&pcnt, (void*)&out };
    hipLaunchCooperativeKernel((void*)fused_all, dim3(NN), dim3(NT),
                               args, 0, stream);
}

// Round 7
// 77.936 us; speedup vs baseline: 1.5972x; 1.5972x over previous
//
#include <hip/hip_runtime.h>
#include <math.h>

#define BB 128   // batch
#define VV 4     // views
#define NN 512   // BB*VV rows
#define DD 128   // feature dim
#define NT 256   // threads per block
#define MAGIC 0x5151FA7Eu   // != 0xAAAAAAAA ws-poison, != 0

// ---------------------------------------------------------------------------
// Single NON-cooperative kernel, one block per anchor (512 blocks, 2/CU).
// R5/R6 showed cg::this_grid().sync() destroys codegen (VGPR 24-32, scratch
// spills, 53 us); this uses a flag-based finalize instead:
//   - each block writes psum/pcnt via device-scope atomic stores,
//     __threadfence(), then flag[a] = MAGIC (device-scope atomic store)
//   - block 0 spins on all 512 flags (device-scope atomic loads at the
//     coherent point -> no cross-XCD staleness), reduces, writes out.
// Init-independent: only requires initial flag != MAGIC (poison is 0xAA..).
// Phases 1-3 are byte-identical to round 4's proven kernel (VGPR ~84).
// ---------------------------------------------------------------------------
__global__ __launch_bounds__(NT)
void fused_all(const float* __restrict__ feat,
               const int* __restrict__ labels,
               float* __restrict__ psum,
               float* __restrict__ pcnt,
               unsigned int* __restrict__ flag,
               float* __restrict__ out) {
    __shared__ float s_ss[NN];
    __shared__ float s_dot[NN];
    __shared__ float s_pos[NN];
    __shared__ float s_neg[NN];
    __shared__ int   s_lab[BB];
    __shared__ int   s_np, s_nn;
    __shared__ float s_wsum[NT / 64];
    __shared__ unsigned int s_wcnt[NT / 64];

    const int a    = blockIdx.x;
    const int tid  = threadIdx.x;
    const int wave = tid >> 6;      // 0..3
    const int lane = tid & 63;
    const int grp  = lane >> 3;     // 8 row-groups of 8 lanes
    const int l8   = lane & 7;

    if (tid < BB) s_lab[tid] = labels[tid];
    if (tid == 0) { s_np = 0; s_nn = 0; }

    // anchor row fragments: this lane's 4 float4s — NAMED scalars (no spill)
    const int ab = a & (BB - 1), av = a >> 7;
    const float4* arow = (const float4*)(feat + (size_t)ab * (VV * DD) + av * DD);
    float4 af0 = arow[l8];
    float4 af1 = arow[l8 + 8];
    float4 af2 = arow[l8 + 16];
    float4 af3 = arow[l8 + 24];

    // Phase 1: fused ss + dot sweep; wave w covers rows [w*128, w*128+128)
    #pragma unroll 4
    for (int it = 0; it < 16; ++it) {
        const int j  = (wave << 7) + (it << 3) + grp;
        const int jb = j & (BB - 1), jv = j >> 7;
        const float4* jrow = (const float4*)(feat + (size_t)jb * (VV * DD) + jv * DD);
        float4 x0 = jrow[l8];
        float4 x1 = jrow[l8 + 8];
        float4 x2 = jrow[l8 + 16];
        float4 x3 = jrow[l8 + 24];

        float ss = 0.f, dt = 0.f;
        ss = fmaf(x0.x, x0.x, fmaf(x0.y, x0.y, fmaf(x0.z, x0.z, fmaf(x0.w, x0.w, ss))));
        ss = fmaf(x1.x, x1.x, fmaf(x1.y, x1.y, fmaf(x1.z, x1.z, fmaf(x1.w, x1.w, ss))));
        ss = fmaf(x2.x, x2.x, fmaf(x2.y, x2.y, fmaf(x2.z, x2.z, fmaf(x2.w, x2.w, ss))));
        ss = fmaf(x3.x, x3.x, fmaf(x3.y, x3.y, fmaf(x3.z, x3.z, fmaf(x3.w, x3.w, ss))));
        dt = fmaf(x0.x, af0.x, fmaf(x0.y, af0.y, fmaf(x0.z, af0.z, fmaf(x0.w, af0.w, dt))));
        dt = fmaf(x1.x, af1.x, fmaf(x1.y, af1.y, fmaf(x1.z, af1.z, fmaf(x1.w, af1.w, dt))));
        dt = fmaf(x2.x, af2.x, fmaf(x2.y, af2.y, fmaf(x2.z, af2.z, fmaf(x2.w, af2.w, dt))));
        dt = fmaf(x3.x, af3.x, fmaf(x3.y, af3.y, fmaf(x3.z, af3.z, fmaf(x3.w, af3.w, dt))));

        #pragma unroll
        for (int off = 4; off > 0; off >>= 1) {
            ss += __shfl_xor(ss, off);
            dt += __shfl_xor(dt, off);
        }
        if (l8 == 0) { s_ss[j] = ss; s_dot[j] = dt; }
    }
    __syncthreads();

    // Phase 2a: distances for j = tid, tid+256
    const float ssa  = s_ss[a];
    const float inva = 1.f / fmaxf(sqrtf(ssa), 1e-12f);
    const float sna  = ssa * inva * inva;
    float dreg[2];
    #pragma unroll
    for (int rnd = 0; rnd < 2; ++rnd) {
        const int j = tid + (rnd << 8);
        float ssj  = s_ss[j];
        float invj = 1.f / fmaxf(sqrtf(ssj), 1e-12f);
        float snj  = ssj * invj * invj;
        float dot  = s_dot[j] * inva * invj;
        float sq   = fmaxf(sna + snj - 2.f * dot, 0.f);
        dreg[rnd]  = (sq > 0.f) ? sqrtf(sq) : 0.f;   // safe_sqrt semantics
    }

    // Phase 2b: ballot compaction into pos/neg lists (8 LDS atomics/block)
    const int la = s_lab[a & (BB - 1)];
    #pragma unroll
    for (int rnd = 0; rnd < 2; ++rnd) {
        const int j = tid + (rnd << 8);
        bool same  = (s_lab[j & (BB - 1)] == la);
        bool ispos = same & (j != a);
        bool isneg = !same;
        unsigned long long mp = __ballot(ispos);
        unsigned long long mn = __ballot(isneg);
        int basep = 0, basen = 0;
        if (lane == 0) {
            basep = atomicAdd(&s_np, (int)__popcll(mp));
            basen = atomicAdd(&s_nn, (int)__popcll(mn));
        }
        basep = __shfl(basep, 0);
        basen = __shfl(basen, 0);
        unsigned long long below = (1ull << lane) - 1ull;
        if (ispos) s_pos[basep + (int)__popcll(mp & below)] = dreg[rnd];
        if (isneg) s_neg[basen + (int)__popcll(mn & below)] = dreg[rnd];
    }
    __syncthreads();

    // Phase 2c: pair loop — sum/count of relu(d_ap - d_an) > 0
    const int np = s_np, nneg = s_nn;
    float lsum = 0.f;
    unsigned int lcnt = 0;
    for (int p = 0; p < np; ++p) {
        float dp = s_pos[p];                 // LDS broadcast
        for (int n = tid; n < nneg; n += NT) {
            float diff = dp - s_neg[n];
            if (diff > 0.f) { lsum += diff; lcnt++; }
        }
    }

    // Phase 3: block reduce -> partials + release flag
    #pragma unroll
    for (int off = 32; off > 0; off >>= 1) {
        lsum += __shfl_down(lsum, off);
        lcnt += __shfl_down(lcnt, off);
    }
    if (lane == 0) { s_wsum[wave] = lsum; s_wcnt[wave] = lcnt; }
    __syncthreads();
    if (tid == 0) {
        float S = s_wsum[0] + s_wsum[1] + s_wsum[2] + s_wsum[3];
        float C = (float)(s_wcnt[0] + s_wcnt[1] + s_wcnt[2] + s_wcnt[3]);
        __hip_atomic_store(&psum[a], S, __ATOMIC_RELAXED, __HIP_MEMORY_SCOPE_AGENT);
        __hip_atomic_store(&pcnt[a], C, __ATOMIC_RELAXED, __HIP_MEMORY_SCOPE_AGENT);
        __threadfence();   // partials visible at device scope before flag
        __hip_atomic_store(&flag[a], MAGIC, __ATOMIC_RELEASE, __HIP_MEMORY_SCOPE_AGENT);
    }

    // Block 0: wait for all 512 flags, then finalize
    if (blockIdx.x == 0) {
        while (__hip_atomic_load(&flag[tid], __ATOMIC_ACQUIRE,
                                 __HIP_MEMORY_SCOPE_AGENT) != MAGIC) {}
        while (__hip_atomic_load(&flag[tid + NT], __ATOMIC_ACQUIRE,
                                 __HIP_MEMORY_SCOPE_AGENT) != MAGIC) {}
        __threadfence();
        float s = __hip_atomic_load(&psum[tid], __ATOMIC_RELAXED, __HIP_MEMORY_SCOPE_AGENT)
                + __hip_atomic_load(&psum[tid + NT], __ATOMIC_RELAXED, __HIP_MEMORY_SCOPE_AGENT);
        float c = __hip_atomic_load(&pcnt[tid], __ATOMIC_RELAXED, __HIP_MEMORY_SCOPE_AGENT)
                + __hip_atomic_load(&pcnt[tid + NT], __ATOMIC_RELAXED, __HIP_MEMORY_SCOPE_AGENT);
        #pragma unroll
        for (int off = 32; off > 0; off >>= 1) {
            s += __shfl_down(s, off);
            c += __shfl_down(c, off);
        }
        __syncthreads();   // s_wsum/s_wcnt reuse safe
        if (lane == 0) { s_wsum[wave] = s; s_wcnt[wave] = (unsigned int)c; }
        __syncthreads();
        if (tid == 0) {
            float S = s_wsum[0] + s_wsum[1] + s_wsum[2] + s_wsum[3];
            float C = (float)(s_wcnt[0] + s_wcnt[1] + s_wcnt[2] + s_wcnt[3]);
            out[0] = (C > 0.f) ? S / C : 0.f;
        }
    }
}

extern "C" void kernel_launch(void* const* d_in, const int* in_sizes, int n_in,
                              void* d_out, int out_size, void* d_ws, size_t ws_size,
                              hipStream_t stream) {
    const float* feat   = (const float*)d_in[0];   // [128, 4, 128] fp32
    const int*   labels = (const int*)d_in[1];     // [128] int32
    float* out = (float*)d_out;

    float*        psum = (float*)d_ws;             // NN floats
    float*        pcnt = psum + NN;                // NN floats
    unsigned int* flag = (unsigned int*)(pcnt + NN); // NN uints

    fused_all<<<NN, NT, 0, stream>>>(feat, labels, psum, pcnt, flag, out);
}